// Round 1
// baseline (144.785 us; speedup 1.0000x reference)
//
#include <hip/hip_runtime.h>
#include <cstdint>

#define CH 192
#define HW 65536
#define PN 64           // pixels per workgroup
#define PITCH 200       // LDS row pitch in bf16 elements (multiple of 8 -> 16B-aligned b128)
#define KB 6            // K blocks (192/32)

#define GAMMA_BOUND 3.814697265625e-06f            // 2^-18
#define PEDESTAL    1.4551915228366852e-11f        // 2^-36
#define BETA_BOUND  1.0000072759550125e-03f        // sqrt(1e-6 + 2^-36)

typedef __attribute__((ext_vector_type(8))) __bf16 bf16x8;
typedef __attribute__((ext_vector_type(4))) float  f32x4;

__device__ __forceinline__ ushort f2bf(float f) {
    union { float f; uint32_t u; } v; v.f = f;
    uint32_t u = v.u;
    return (ushort)((u + 0x7FFFu + ((u >> 16) & 1u)) >> 16);  // RNE
}
__device__ __forceinline__ float bf2f(ushort h) {
    union { uint32_t u; float f; } v; v.u = ((uint32_t)h) << 16;
    return v.f;
}

// ---- prep: reparam params, convert G to bf16, into workspace ----
__global__ __launch_bounds__(256) void gsdn_prep(
    const float* __restrict__ beta, const float* __restrict__ gamma,
    const float* __restrict__ beta2, const float* __restrict__ gamma2,
    ushort* __restrict__ g2bf, ushort* __restrict__ g1bf,
    float* __restrict__ b2r, float* __restrict__ b1r)
{
    int i = blockIdx.x * 256 + threadIdx.x;
    if (i < CH * CH) {
        float g = fmaxf(gamma2[i], GAMMA_BOUND);
        g2bf[i] = f2bf(g * g - PEDESTAL);
        float h = fmaxf(gamma[i], GAMMA_BOUND);
        g1bf[i] = f2bf(h * h - PEDESTAL);
    }
    if (i < CH) {
        float b = fmaxf(beta2[i], BETA_BOUND);
        b2r[i] = b * b - PEDESTAL;
        float a = fmaxf(beta[i], BETA_BOUND);
        b1r[i] = a * a - PEDESTAL;
    }
}

// ---- main fused kernel ----
__global__ __launch_bounds__(256, 2) void gsdn_main(
    const float* __restrict__ X,
    const ushort* __restrict__ g2bf, const ushort* __restrict__ g1bf,
    const float* __restrict__ b2r, const float* __restrict__ b1r,
    float* __restrict__ Y)
{
    __shared__ ushort Xs[PN * PITCH];   // v tile, bf16, [n][c]
    __shared__ ushort Qs[PN * PITCH];   // x*x tile, bf16, [n][c]

    const int tid  = threadIdx.x;
    const int wave = tid >> 6;
    const int lane = tid & 63;

    const int wg = blockIdx.x;
    const int b  = wg >> 10;                 // 1024 WGs per batch image
    const int n0 = (wg & 1023) * PN;

    const float* Xb = X + (size_t)b * CH * HW + n0;
    float*       Yb = Y + (size_t)b * CH * HW + n0;

    // ---- stage X tile -> LDS (bf16, transposed [n][c]) ----
    {
        const int n  = tid & 63;
        const int g0 = tid >> 6;             // 0..3
        #pragma unroll
        for (int i = 0; i < 12; ++i) {
            const int cb = 4 * (g0 + 4 * i);
            float x0 = Xb[(size_t)(cb + 0) * HW + n];
            float x1 = Xb[(size_t)(cb + 1) * HW + n];
            float x2 = Xb[(size_t)(cb + 2) * HW + n];
            float x3 = Xb[(size_t)(cb + 3) * HW + n];
            ushort4 p;
            p.x = f2bf(x0); p.y = f2bf(x1); p.z = f2bf(x2); p.w = f2bf(x3);
            *(ushort4*)&Xs[n * PITCH + cb] = p;
        }
    }
    __syncthreads();

    const int lm = lane & 15;       // pixel-in-block / D column
    const int lh = lane >> 4;       // 0..3 (k block / D row group)

    // ---- GEMM1: m = G2 @ v ----
    f32x4 acc[3][4];
    #pragma unroll
    for (int o = 0; o < 3; ++o)
        #pragma unroll
        for (int nb = 0; nb < 4; ++nb)
            acc[o][nb] = (f32x4){0.f, 0.f, 0.f, 0.f};

    #pragma unroll
    for (int kb = 0; kb < KB; ++kb) {
        bf16x8 bfr[4];
        #pragma unroll
        for (int nb = 0; nb < 4; ++nb)
            bfr[nb] = *(const bf16x8*)&Xs[(nb * 16 + lm) * PITCH + kb * 32 + 8 * lh];
        #pragma unroll
        for (int o = 0; o < 3; ++o) {
            const int orow = (3 * wave + o) * 16 + lm;
            bf16x8 afr = *(const bf16x8*)(g2bf + orow * CH + kb * 32 + 8 * lh);
            #pragma unroll
            for (int nb = 0; nb < 4; ++nb)
                acc[o][nb] = __builtin_amdgcn_mfma_f32_16x16x32_bf16(afr, bfr[nb], acc[o][nb], 0, 0, 0);
        }
    }

    // ---- x = v - (m + b2); Qs = (x*x) bf16; keep x in acc ----
    #pragma unroll
    for (int o = 0; o < 3; ++o) {
        const int cb = (3 * wave + o) * 16 + 4 * lh;
        const float4 b2v = *(const float4*)(b2r + cb);
        #pragma unroll
        for (int nb = 0; nb < 4; ++nb) {
            const int n = nb * 16 + lm;
            ushort4 vv = *(const ushort4*)&Xs[n * PITCH + cb];
            float x0 = bf2f(vv.x) - (acc[o][nb][0] + b2v.x);
            float x1 = bf2f(vv.y) - (acc[o][nb][1] + b2v.y);
            float x2 = bf2f(vv.z) - (acc[o][nb][2] + b2v.z);
            float x3 = bf2f(vv.w) - (acc[o][nb][3] + b2v.w);
            acc[o][nb][0] = x0; acc[o][nb][1] = x1;
            acc[o][nb][2] = x2; acc[o][nb][3] = x3;
            ushort4 q;
            q.x = f2bf(x0 * x0); q.y = f2bf(x1 * x1);
            q.z = f2bf(x2 * x2); q.w = f2bf(x3 * x3);
            *(ushort4*)&Qs[n * PITCH + cb] = q;
        }
    }
    __syncthreads();

    // ---- GEMM2: S = G1 @ (x*x) ----
    f32x4 acs[3][4];
    #pragma unroll
    for (int o = 0; o < 3; ++o)
        #pragma unroll
        for (int nb = 0; nb < 4; ++nb)
            acs[o][nb] = (f32x4){0.f, 0.f, 0.f, 0.f};

    #pragma unroll
    for (int kb = 0; kb < KB; ++kb) {
        bf16x8 bfr[4];
        #pragma unroll
        for (int nb = 0; nb < 4; ++nb)
            bfr[nb] = *(const bf16x8*)&Qs[(nb * 16 + lm) * PITCH + kb * 32 + 8 * lh];
        #pragma unroll
        for (int o = 0; o < 3; ++o) {
            const int orow = (3 * wave + o) * 16 + lm;
            bf16x8 afr = *(const bf16x8*)(g1bf + orow * CH + kb * 32 + 8 * lh);
            #pragma unroll
            for (int nb = 0; nb < 4; ++nb)
                acs[o][nb] = __builtin_amdgcn_mfma_f32_16x16x32_bf16(afr, bfr[nb], acs[o][nb], 0, 0, 0);
        }
    }

    // ---- out = x * rsqrt(S + b1) ----
    #pragma unroll
    for (int o = 0; o < 3; ++o) {
        const int cb = (3 * wave + o) * 16 + 4 * lh;
        const float4 b1v = *(const float4*)(b1r + cb);
        #pragma unroll
        for (int nb = 0; nb < 4; ++nb) {
            const int n = nb * 16 + lm;
            float r0 = rsqrtf(acs[o][nb][0] + b1v.x);
            float r1 = rsqrtf(acs[o][nb][1] + b1v.y);
            float r2 = rsqrtf(acs[o][nb][2] + b1v.z);
            float r3 = rsqrtf(acs[o][nb][3] + b1v.w);
            Yb[(size_t)(cb + 0) * HW + n] = acc[o][nb][0] * r0;
            Yb[(size_t)(cb + 1) * HW + n] = acc[o][nb][1] * r1;
            Yb[(size_t)(cb + 2) * HW + n] = acc[o][nb][2] * r2;
            Yb[(size_t)(cb + 3) * HW + n] = acc[o][nb][3] * r3;
        }
    }
}

extern "C" void kernel_launch(void* const* d_in, const int* in_sizes, int n_in,
                              void* d_out, int out_size, void* d_ws, size_t ws_size,
                              hipStream_t stream) {
    const float* X      = (const float*)d_in[0];
    const float* beta   = (const float*)d_in[1];
    const float* gamma  = (const float*)d_in[2];
    const float* beta2  = (const float*)d_in[3];
    const float* gamma2 = (const float*)d_in[4];
    float* Y = (float*)d_out;

    ushort* g2bf = (ushort*)d_ws;
    ushort* g1bf = g2bf + CH * CH;
    float*  b2r  = (float*)(g1bf + CH * CH);
    float*  b1r  = b2r + CH;

    hipLaunchKernelGGL(gsdn_prep, dim3((CH * CH + 255) / 256), dim3(256), 0, stream,
                       beta, gamma, beta2, gamma2, g2bf, g1bf, b2r, b1r);
    hipLaunchKernelGGL(gsdn_main, dim3(4 * (HW / PN)), dim3(256), 0, stream,
                       X, g2bf, g1bf, b2r, b1r, Y);
}